// Round 19
// baseline (45.435 us; speedup 1.0000x reference)
//
#include <hip/hip_runtime.h>

// Fully-fused cascaded-biquad IIR (DF2T) via linear state-space chunking.
// R19 = R18 skeleton with x RESIDENT IN NAMED REGISTERS between P1 and P4:
//   P1: gll dense staging -> LDS -> read into x0..x15 while computing the
//       zero-init chunk state (capture is free: same ds_read).
//   scan: R18 verbatim (shfl levels 0..5 + Wf-exchange levels 6..8).
//   P4: NO global reads, NO staging, NO vmcnt drains -- compute out4 from
//       registers into the per-wave LDS write-transpose, store out dense.
// Kernel memory = read x once + write y once. LDS exactly 65536 (the
// 2-blocks/CU cliff). R4/R5's register-resident attempts failed ONLY due
// to __launch_bounds__(512,4)'s 64-VGPR cap -- not used here.

namespace {
constexpr int NS     = 4;
constexpr int BATCH  = 512;
constexpr int TLEN   = 32768;      // 2^15
constexpr int NSTATE = 8;
constexpr int P      = 512;        // chunks per batch = threads per block
constexpr int L      = TLEN / P;   // 64 steps per chunk
constexpr int LQ     = L / 4;      // 16 float4 per chunk
constexpr int LOG2P  = 9;
constexpr int LOG2L  = 6;
constexpr int NSQ    = LOG2L + LOG2P - 1;  // 14 squaring iterations
}

#if defined(__has_builtin)
#  if __has_builtin(__builtin_amdgcn_global_load_lds)
#    define USE_GLL 1
#  endif
#endif
#ifndef USE_GLL
#  define USE_GLL 0
#endif

#define WAIT_VM0 do { asm volatile("s_waitcnt vmcnt(0)" ::: "memory"); \
                      __builtin_amdgcn_sched_barrier(0); } while (0)
#define WAIT_LGKM0 do { asm volatile("s_waitcnt lgkmcnt(0)" ::: "memory"); \
                        __builtin_amdgcn_sched_barrier(0); } while (0)

__device__ __forceinline__ void load_coefs(const float* __restrict__ bc,
                                           const float* __restrict__ ac,
                                           float b0[NS], float b1[NS], float b2[NS],
                                           float a1[NS], float a2[NS]) {
#pragma unroll
  for (int k = 0; k < NS; ++k) {
    b0[k] = bc[3 * k];
    b1[k] = bc[3 * k + 1];
    b2[k] = bc[3 * k + 2];
    a1[k] = ac[2 * k];
    a2[k] = ac[2 * k + 1];
  }
}

// One time-step through the 4-section cascade (matches reference exactly).
__device__ __forceinline__ float step_cascade(float sig,
                                              const float b0[NS], const float b1[NS],
                                              const float b2[NS], const float a1[NS],
                                              const float a2[NS],
                                              float s1[NS], float s2[NS]) {
#pragma unroll
  for (int k = 0; k < NS; ++k) {
    float y = fmaf(b0[k], sig, s1[k]);
    s1[k]   = fmaf(-a1[k], y, fmaf(b1[k], sig, s2[k]));
    s2[k]   = fmaf(-a2[k], y, b2[k] * sig);
    sig = y;
  }
  return sig;
}

#define CO b0, b1, b2, a1, a2

__device__ __forceinline__ void adv4(const float4 u,
                                     const float b0[NS], const float b1[NS],
                                     const float b2[NS], const float a1[NS],
                                     const float a2[NS], float s1[NS], float s2[NS]) {
  (void)step_cascade(u.x, CO, s1, s2);
  (void)step_cascade(u.y, CO, s1, s2);
  (void)step_cascade(u.z, CO, s1, s2);
  (void)step_cascade(u.w, CO, s1, s2);
}

__device__ __forceinline__ float4 out4(const float4 u,
                                       const float b0[NS], const float b1[NS],
                                       const float b2[NS], const float a1[NS],
                                       const float a2[NS], float s1[NS], float s2[NS]) {
  float4 y;
  y.x = step_cascade(u.x, CO, s1, s2);
  y.y = step_cascade(u.y, CO, s1, s2);
  y.z = step_cascade(u.z, CO, s1, s2);
  y.w = step_cascade(u.w, CO, s1, s2);
  return y;
}

// Stage one half-tile (64 chunks x 8 f4 = 8KB): linear LDS dest, per-lane
// pre-swizzled global source (R12/R13-validated). Dense 128B lines.
__device__ __forceinline__ void stage_ht(const float4* __restrict__ gx_w,
                                         float4* R, int lane, int ht) {
#if USE_GLL
#pragma unroll
  for (int j = 0; j < 8; ++j) {
    const int cc = j * 8 + (lane >> 3);
    const int qq = lane & 7;
    const float4* g = gx_w + cc * 16 + ht * 8 + (qq ^ (cc & 7));
    __builtin_amdgcn_global_load_lds(
        (const __attribute__((address_space(1))) void*)g,
        (__attribute__((address_space(3))) void*)&R[j * 64], 16, 0, 0);
  }
#else
#pragma unroll
  for (int j = 0; j < 8; ++j) {
    const int cc = j * 8 + (lane >> 3);
    const int qq = lane & 7;
    R[j * 64 + lane] = gx_w[cc * 16 + ht * 8 + (qq ^ (cc & 7))];
  }
#endif
}

__global__ __launch_bounds__(P) void k_fused(const float* __restrict__ x,
                                             const float* __restrict__ bc,
                                             const float* __restrict__ ac,
                                             float* __restrict__ out) {
  // 64 KiB arena. P1 staging & P4 write-transpose: wave wv owns f4
  // [wv*512, +512). Scan: Msf = floats [0,576), Wf = floats [576,5184).
  __shared__ float4 arena[4096];
  float* Msf = reinterpret_cast<float*>(arena);
  float* Wf  = reinterpret_cast<float*>(arena) + 576;

  const int t    = threadIdx.x;
  const int lane = t & 63;
  const int wv   = t >> 6;
  const int swz  = lane & 7;
  float4* __restrict__ R = arena + (wv << 9);

  float b0[NS], b1[NS], b2[NS], a1[NS], a2[NS];
  load_coefs(bc, ac, b0, b1, b2, a1, a2);

  const float4* __restrict__ gx_w = reinterpret_cast<const float4*>(x) +
      (size_t)blockIdx.x * (P * LQ) + ((size_t)wv << 10);
  float4* __restrict__ gy_w = reinterpret_cast<float4*>(out) +
      (size_t)blockIdx.x * (P * LQ) + ((size_t)wv << 10);

  // ---- P1 HT0 staging (HBM latency hides under Ms squarings) ----
  stage_ht(gx_w, R, lane, 0);

  // ---- Ms squarings in-register (wave 0 only), stored AFTER P1 barrier ----
  float mpow[9];
#pragma unroll
  for (int i = 0; i < 9; ++i) mpow[i] = 0.0f;
  if (t < 64) {
    const int r = lane >> 3, c = lane & 7;
    float p1[NS] = {0.f, 0.f, 0.f, 0.f};
    float p2[NS] = {0.f, 0.f, 0.f, 0.f};
    if (c & 1) p2[c >> 1] = 1.0f; else p1[c >> 1] = 1.0f;
    (void)step_cascade(0.0f, CO, p1, p2);
    float m = (r & 1) ? p2[r >> 1] : p1[r >> 1];  // A element (r,c)
#pragma unroll
    for (int it = 0; it < NSQ; ++it) {
      float acc = 0.0f;
#pragma unroll
      for (int k = 0; k < NSTATE; ++k)
        acc = fmaf(__shfl(m, r * 8 + k), __shfl(m, k * 8 + c), acc);
      m = acc;
      if (it >= LOG2L - 1) mpow[it - (LOG2L - 1)] = m;
    }
  }

  // ---- P1: chunk state from zero; CAPTURE x into named registers ----
  float s1[NS] = {0.f, 0.f, 0.f, 0.f};
  float s2[NS] = {0.f, 0.f, 0.f, 0.f};
  float4 x0, x1, x2, x3, x4, x5, x6, x7, x8, x9, x10, x11, x12, x13, x14, x15;

#define P1Q(Q, XV) do { XV = R[lane * 8 + ((Q) ^ swz)]; adv4(XV, CO, s1, s2); } while (0)
  WAIT_VM0;
  P1Q(0, x0); P1Q(1, x1); P1Q(2, x2); P1Q(3, x3);
  P1Q(4, x4); P1Q(5, x5); P1Q(6, x6); P1Q(7, x7);
  WAIT_LGKM0;  // WAR: HT0 ds_reads retired before HT1 overwrites
  stage_ht(gx_w, R, lane, 1);
  WAIT_VM0;
  P1Q(0, x8);  P1Q(1, x9);  P1Q(2, x10); P1Q(3, x11);
  P1Q(4, x12); P1Q(5, x13); P1Q(6, x14); P1Q(7, x15);
#undef P1Q

  float w[NSTATE];
#pragma unroll
  for (int k = 0; k < NS; ++k) { w[2 * k] = s1[k]; w[2 * k + 1] = s2[k]; }

  __syncthreads();  // #1: all P1 LDS traffic done; arena repurposed
  if (t < 64) {
#pragma unroll
    for (int d = 0; d < LOG2P; ++d) Msf[d * 64 + t] = mpow[d];
  }
  __syncthreads();  // #2: Msf visible to all waves

  // ---- scan levels 0..5: in-wave Kogge-Stone via __shfl (no barriers) ----
#pragma unroll
  for (int d = 0; d < 6; ++d) {
    const int off = 1 << d;
    const int src = (lane >= off) ? (lane - off) : lane;
    float prev[NSTATE];
#pragma unroll
    for (int r = 0; r < NSTATE; ++r) prev[r] = __shfl(w[r], src);
    if (lane >= off) {
#pragma unroll
      for (int r = 0; r < NSTATE; ++r) {
        float acc = w[r];
#pragma unroll
        for (int k = 0; k < NSTATE; ++k)
          acc = fmaf(Msf[d * 64 + r * 8 + k], prev[k], acc);  // broadcast
        w[r] = acc;
      }
    }
  }

  // ---- scan levels 6..8: Wf-exchange (R13/R18 verbatim) ----
  for (int d = 6; d < LOG2P; ++d) {
#pragma unroll
    for (int r = 0; r < NSTATE; ++r) Wf[t * 9 + r] = w[r];
    __syncthreads();
    if (t >= (1 << d)) {
      const int src = (t - (1 << d)) * 9;
      float prev[NSTATE];
#pragma unroll
      for (int r = 0; r < NSTATE; ++r) prev[r] = Wf[src + r];
#pragma unroll
      for (int r = 0; r < NSTATE; ++r) {
        float acc = w[r];
#pragma unroll
        for (int k = 0; k < NSTATE; ++k)
          acc = fmaf(Msf[d * 64 + r * 8 + k], prev[k], acc);  // broadcast
        w[r] = acc;
      }
    }
    __syncthreads();
  }

  // ---- exclusive shift -> s_init in registers ----
#pragma unroll
  for (int r = 0; r < NSTATE; ++r) Wf[t * 9 + r] = w[r];
  __syncthreads();
  {
    const int src = (t == 0 ? 0 : t - 1) * 9;
#pragma unroll
    for (int k = 0; k < NS; ++k) {
      s1[k] = (t == 0) ? 0.0f : Wf[src + 2 * k];
      s2[k] = (t == 0) ? 0.0f : Wf[src + 2 * k + 1];
    }
  }
  __syncthreads();  // scan reads done before P4 write-transpose uses arena

  // ---- P4: replay from registers (NO global reads, NO staging) ----
#define P4Q(Q, XV) R[lane * 8 + ((Q) ^ swz)] = out4(XV, CO, s1, s2)
  // half-tile 0: f4 0..7
  P4Q(0, x0); P4Q(1, x1); P4Q(2, x2); P4Q(3, x3);
  P4Q(4, x4); P4Q(5, x5); P4Q(6, x6); P4Q(7, x7);
  WAIT_LGKM0;  // writes committed before transpose-out reads
#pragma unroll
  for (int j = 0; j < 8; ++j) {
    const int cc = j * 8 + (lane >> 3);
    const int qq = lane & 7;
    const float4 v = R[j * 64 + lane];
    gy_w[cc * 16 + (qq ^ (cc & 7))] = v;  // dense 128B lines
  }
  WAIT_LGKM0;  // WAR: transpose reads done before half-tile 1 overwrites
  // half-tile 1: f4 8..15
  P4Q(0, x8);  P4Q(1, x9);  P4Q(2, x10); P4Q(3, x11);
  P4Q(4, x12); P4Q(5, x13); P4Q(6, x14); P4Q(7, x15);
  WAIT_LGKM0;
#pragma unroll
  for (int j = 0; j < 8; ++j) {
    const int cc = j * 8 + (lane >> 3);
    const int qq = lane & 7;
    const float4 v = R[j * 64 + lane];
    gy_w[cc * 16 + 8 + (qq ^ (cc & 7))] = v;
  }
#undef P4Q
}

extern "C" void kernel_launch(void* const* d_in, const int* in_sizes, int n_in,
                              void* d_out, int out_size, void* d_ws, size_t ws_size,
                              hipStream_t stream) {
  const float* x  = (const float*)d_in[0];  // (B, T, 1)
  const float* bc = (const float*)d_in[1];  // (NS, 3)
  const float* ac = (const float*)d_in[2];  // (NS, 2)
  float* out = (float*)d_out;               // (B, T, 1)

  k_fused<<<BATCH, P, 0, stream>>>(x, bc, ac, out);
}